// Round 15
// baseline (83.672 us; speedup 1.0000x reference)
//
#include <hip/hip_runtime.h>
#include <cfloat>

#define NFEAT 256
#define BATCH 4096
#define MTOT  16384
#define NSTRIP 32
#define STRIPW 512
#define NCH 16                // 32-col chunks per strip
#define UMARGIN 0.75f

typedef __attribute__((ext_vector_type(8))) short bf16x8;
typedef __attribute__((ext_vector_type(16))) float f32x16;

#define GP(p)   ((const __attribute__((address_space(1))) void*)(p))
#define LDSP(p) ((__attribute__((address_space(3))) void*)(p))

__device__ __forceinline__ unsigned bf16pack(float a, float b) {
    unsigned ua = __float_as_uint(a), ub = __float_as_uint(b);
    unsigned ra = (ua + 0x7fffu + ((ua >> 16) & 1u)) >> 16;
    unsigned rb = (ub + 0x7fffu + ((ub >> 16) & 1u)) >> 16;
    return ra | (rb << 16);
}

// ---------------------------------------------------------------------------
// Prep (fused, one launch): waves 0..4095 -> A rows (bf16 row-major + a2);
// waves 4096..4607 -> B 32-col groups in 32x32x16 MFMA-FRAGMENT order + b2.
// B layout: group g, k-step ks (K=16): 1024-B block; lane l's 16 B = col
// g*32+(l&31), bf16 elems ks*16+(l>>5)*8 .. +8.
// ---------------------------------------------------------------------------
__global__ __launch_bounds__(256) void prep_kernel(
        const float* __restrict__ xb, const float* __restrict__ w,
        uint2* __restrict__ Abf, uint4* __restrict__ Bfr,
        float* __restrict__ a2, float* __restrict__ b2) {
    const int t = threadIdx.x, l = t & 63;
    const int wv = blockIdx.x * 4 + (t >> 6);
    if (wv < BATCH) {
        float4 v = ((const float4*)(xb + (size_t)wv * NFEAT))[l];
        Abf[(size_t)wv * 64 + l] = make_uint2(bf16pack(v.x, v.y), bf16pack(v.z, v.w));
        float s = v.x * v.x + v.y * v.y + v.z * v.z + v.w * v.w;
        #pragma unroll
        for (int off = 32; off > 0; off >>= 1) s += __shfl_down(s, off);
        if (l == 0) a2[wv] = s;
    } else {
        const int g = wv - BATCH;              // 0..511
        const int col = g * 32 + (l & 31);
        const float4* src = (const float4*)(w + (size_t)col * NFEAT);
        float ss = 0.f;
        #pragma unroll
        for (int ks = 0; ks < 16; ++ks) {
            float4 v0 = src[ks * 4 + (l >> 5) * 2];
            float4 v1 = src[ks * 4 + (l >> 5) * 2 + 1];
            ss += v0.x * v0.x + v0.y * v0.y + v0.z * v0.z + v0.w * v0.w
                + v1.x * v1.x + v1.y * v1.y + v1.z * v1.z + v1.w * v1.w;
            uint4 o;
            o.x = bf16pack(v0.x, v0.y);
            o.y = bf16pack(v0.z, v0.w);
            o.z = bf16pack(v1.x, v1.y);
            o.w = bf16pack(v1.z, v1.w);
            Bfr[(size_t)g * 1024 + ks * 64 + l] = o;
        }
        ss += __shfl_xor(ss, 32);              // both K-halves of same col
        if (l < 32) b2[g * 32 + l] = ss;
    }
}

// ---------------------------------------------------------------------------
// Main: 32x32x16 MFMA (2x FLOP/instruction vs all prior rounds; 2495 TF
// ceiling m119). Grid 512 (2/CU) x 256 thr (4 waves x 64 rows). Wave: A
// panel afr[2][16] = 128 pinned VGPRs; per 32-col chunk: 16 ds_read_b128 +
// 32 MFMA (2 chains of 16). Ring 4 x 16 KB + b2 2 KB = 66 KB LDS; fine
// phases: {vmcnt(8) -> barrier -> stage c+3 -> MFMA (setprio) -> fold}.
// Bfr fragment-ordered: stage + ds_read lane-linear, conflict-free.
// min-dist == max-(dot - b2/2); per-lane top-2, 4-bit chunk id in mantissa.
// C/D: col=lane&31, row=(reg&3)+8*(reg>>2)+4*(lane>>5)  [m74/m101].
// ---------------------------------------------------------------------------
__global__ __launch_bounds__(256, 2) void som_mfma_kernel(
        const unsigned short* __restrict__ Abf, const unsigned short* __restrict__ Bfr,
        const float* __restrict__ b2, float* __restrict__ part) {
    __shared__ char smem[67584];    // ring 4 x 16 KB | b2 strip 2 KB

    const int t = threadIdx.x, l = t & 63;
    const int wid = t >> 6;
    const int x = blockIdx.x & 7, y = blockIdx.x >> 3;   // y: 0..63
    const int strip = x * 4 + (y & 3);                   // 4 strips per XCD
    const int m0 = (y >> 2) * 256 + wid * 64;            // 64 rows per wave

    // ---- A panel -> 128 regs (32x32x16 frag layout), loaded + pinned ----
    // lane l: rows m0 + mt*32 + (l&31); k = ks*16 + (l>>5)*8 .. +8
    const char* gA = (const char*)Abf + (size_t)(m0 + (l & 31)) * 512 + (l >> 5) * 16;
    bf16x8 afr[2][16];
    #pragma unroll
    for (int mt = 0; mt < 2; ++mt)
        #pragma unroll
        for (int ks = 0; ks < 16; ++ks)
            afr[mt][ks] = *(const bf16x8*)(gA + mt * 32 * 512 + ks * 32);

    // ---- staging: chunk = one 32-col group = 16 KB = 4 ops/thread ----
    const char* gBs = (const char*)Bfr + (size_t)strip * (NCH * 16384) + t * 16;
#define STAGE(slot, c) {                                                         \
        _Pragma("unroll")                                                        \
        for (int i_ = 0; i_ < 4; ++i_)                                           \
            __builtin_amdgcn_global_load_lds(                                    \
                GP(gBs + (size_t)(c) * 16384 + i_ * 4096),                       \
                LDSP(smem + (slot) * 16384 + i_ * 4096 + t * 16), 16, 0, 0);     \
    }

    // prologue: b2 strip (2 ops) + chunks 0,1,2 into slots 0,1,2
    #pragma unroll
    for (int j = 0; j < 2; ++j)
        __builtin_amdgcn_global_load_lds(
            GP((const char*)b2 + (size_t)strip * 2048 + j * 1024 + t * 4),
            LDSP(smem + 65536 + j * 1024 + t * 4), 4, 0, 0);
    STAGE(0, 0) STAGE(1, 1) STAGE(2, 2)

    // pin A (forces A-wait here; the 14 staging ops stay in flight)
    #pragma unroll
    for (int mt = 0; mt < 2; ++mt)
        #pragma unroll
        for (int ks = 0; ks < 16; ++ks)
            asm volatile("" : "+v"(afr[mt][ks]));

    float r0[2][16], r1[2][16];
    #pragma unroll
    for (int mt = 0; mt < 2; ++mt)
        #pragma unroll
        for (int r = 0; r < 16; ++r) { r0[mt][r] = -FLT_MAX; r1[mt][r] = -FLT_MAX; }

    for (int c = 0; c < NCH; ++c) {
        // counted drain: chunk c landed; c+1, c+2 (8 ops) stay in flight
        if      (c < 14) asm volatile("s_waitcnt vmcnt(8)" ::: "memory");
        else if (c == 14) asm volatile("s_waitcnt vmcnt(4)" ::: "memory");
        else              asm volatile("s_waitcnt vmcnt(0)" ::: "memory");
        __builtin_amdgcn_s_barrier();
        asm volatile("" ::: "memory");

        if (c + 3 < NCH) STAGE((c + 3) & 3, c + 3)   // slot (c-1)&3: freed

        const float b2c = *(const float*)(smem + 65536 + (c * 32 + (l & 31)) * 4);
        const float bi = -0.5f * b2c;
        f32x16 acc0, acc1;
        #pragma unroll
        for (int r = 0; r < 16; ++r) { acc0[r] = bi; acc1[r] = bi; }

        const char* buf = smem + (c & 3) * 16384;
        __builtin_amdgcn_s_setprio(1);
        #pragma unroll
        for (int ks = 0; ks < 16; ++ks) {
            bf16x8 bf = *(const bf16x8*)(buf + ks * 1024 + l * 16);
            acc0 = __builtin_amdgcn_mfma_f32_32x32x16_bf16(afr[0][ks], bf, acc0, 0, 0, 0);
            acc1 = __builtin_amdgcn_mfma_f32_32x32x16_bf16(afr[1][ks], bf, acc1, 0, 0, 0);
        }
        __builtin_amdgcn_s_setprio(0);

        // top-2 fold: 4-bit chunk id in low mantissa bits (3 VALU/elem)
        const unsigned idn = (unsigned)c;
        #pragma unroll
        for (int r = 0; r < 16; ++r) {
            float pa = __uint_as_float((__float_as_uint(acc0[r]) & 0xFFFFFFF0u) | idn);
            float na = __builtin_amdgcn_fmed3f(r0[0][r], r1[0][r], pa);
            r0[0][r] = fmaxf(r0[0][r], pa);
            r1[0][r] = na;
            float pb = __uint_as_float((__float_as_uint(acc1[r]) & 0xFFFFFFF0u) | idn);
            float nb = __builtin_amdgcn_fmed3f(r0[1][r], r1[1][r], pb);
            r0[1][r] = fmaxf(r0[1][r], pb);
            r1[1][r] = nb;
        }
    }

    // ---- per-row merge over the 32 lane-cols (repack 9-bit id: chunk<<5 |
    //      lane-col); shfl widths <32 stay within each half-wave; leaders
    //      (l&31)==0 of each half own disjoint rows -> direct global write.
    #pragma unroll
    for (int mt = 0; mt < 2; ++mt)
        #pragma unroll
        for (int r = 0; r < 16; ++r) {
            unsigned u0 = __float_as_uint(r0[mt][r]);
            unsigned u1 = __float_as_uint(r1[mt][r]);
            u0 = (u0 & 0xFFFFFE00u) | ((u0 & 15u) << 5) | (unsigned)(l & 31);
            u1 = (u1 & 0xFFFFFE00u) | ((u1 & 15u) << 5) | (unsigned)(l & 31);
            float v0 = __uint_as_float(u0), v1 = __uint_as_float(u1);
            #pragma unroll
            for (int off = 1; off < 32; off <<= 1) {
                float o0 = __shfl_xor(v0, off), o1 = __shfl_xor(v1, off);
                float nv1 = fmaxf(fminf(v0, o0), fmaxf(v1, o1));
                v0 = fmaxf(v0, o0);
                v1 = nv1;
            }
            if ((l & 31) == 0) {
                int row = m0 + mt * 32 + (r & 3) + 8 * (r >> 2) + 4 * (l >> 5);
                ((float2*)part)[(size_t)row * NSTRIP + strip] = make_float2(v0, v1);
            }
        }
#undef STAGE
}

// ---------------------------------------------------------------------------
// Refine: 1 wave per row over 64 packed entries (32 strips x top-2); exact
// fp32+sqrt recompute of candidates within margin; (dist, idx) argmin.
// ---------------------------------------------------------------------------
__global__ __launch_bounds__(256) void refine_kernel(
        const float* __restrict__ xb, const float* __restrict__ w,
        const float* __restrict__ a2, const float* __restrict__ b2,
        const float* __restrict__ part, int* __restrict__ out) {
    const int t = threadIdx.x, l = t & 63;
    const int row = blockIdx.x * 4 + (t >> 6);

    const float v = part[(size_t)row * (NSTRIP * 2) + l];
    float mx = v;
    #pragma unroll
    for (int off = 1; off < 64; off <<= 1) mx = fmaxf(mx, __shfl_xor(mx, off));
    const float cut = mx - UMARGIN;

    unsigned long long key = ~0ull;
    if (v >= cut) {
        unsigned b = __float_as_uint(v);
        int c5 = b & 31, c4 = (b >> 5) & 15, strip = l >> 1;
        int col = strip * STRIPW + c4 * 32 + c5;
        const float4* xr = (const float4*)(xb + (size_t)row * NFEAT);
        const float4* wr = (const float4*)(w + (size_t)col * NFEAT);
        float s0 = 0.f, s1 = 0.f, s2 = 0.f, s3 = 0.f;
        #pragma unroll
        for (int k = 0; k < 16; ++k) {
            float4 x0 = xr[4 * k + 0], w0 = wr[4 * k + 0];
            float4 x1 = xr[4 * k + 1], w1 = wr[4 * k + 1];
            float4 x2 = xr[4 * k + 2], w2 = wr[4 * k + 2];
            float4 x3 = xr[4 * k + 3], w3 = wr[4 * k + 3];
            s0 += x0.x * w0.x + x0.y * w0.y + x0.z * w0.z + x0.w * w0.w;
            s1 += x1.x * w1.x + x1.y * w1.y + x1.z * w1.z + x1.w * w1.w;
            s2 += x2.x * w2.x + x2.y * w2.y + x2.z * w2.z + x2.w * w2.w;
            s3 += x3.x * w3.x + x3.y * w3.y + x3.z * w3.z + x3.w * w3.w;
        }
        float dot = (s0 + s1) + (s2 + s3);
        float dd = a2[row] + b2[col] - 2.f * dot;
        float s = sqrtf(fmaxf(dd, 0.f));
        key = ((unsigned long long)__float_as_uint(s) << 32) | (unsigned)col;
    }
    #pragma unroll
    for (int off = 1; off < 64; off <<= 1) {
        unsigned long long o = __shfl_xor(key, off);
        key = o < key ? o : key;
    }
    if (l == 0) {
        int idx = (int)(key & 0xffffffffu);
        out[2 * row]     = idx >> 7;
        out[2 * row + 1] = idx & 127;
    }
}

extern "C" void kernel_launch(void* const* d_in, const int* in_sizes, int n_in,
                              void* d_out, int out_size, void* d_ws, size_t ws_size,
                              hipStream_t stream) {
    const float* xb = (const float*)d_in[0];   // (4096, 256)
    const float* w  = (const float*)d_in[1];   // (16384, 256)
    int* out = (int*)d_out;

    char* ws = (char*)d_ws;
    unsigned short* Abf = (unsigned short*)ws;                 // 2 MB
    unsigned short* Bfr = (unsigned short*)(ws + (2u << 20));  // 8 MB (frag order)
    float* a2   = (float*)(ws + (10u << 20));                  // 16 KB
    float* b2   = (float*)(ws + (10u << 20) + (64u << 10));    // 64 KB
    float* part = (float*)(ws + (10u << 20) + (128u << 10));   // 1 MB

    prep_kernel<<<(BATCH + 512) / 4, 256, 0, stream>>>(xb, w, (uint2*)Abf,
                                                       (uint4*)Bfr, a2, b2);
    som_mfma_kernel<<<512, 256, 0, stream>>>(Abf, Bfr, b2, part);
    refine_kernel<<<BATCH / 4, 256, 0, stream>>>(xb, w, a2, b2, part, out);
}

// Round 16
// 69.234 us; speedup vs baseline: 1.2085x; 1.2085x over previous
//
#include <hip/hip_runtime.h>
#include <cfloat>

#define NFEAT 256
#define BATCH 4096
#define MTOT  16384
#define NSTRIP 16
#define STRIPW 1024
#define NH 32                 // 32-col chunks per strip
#define UMARGIN 0.75f

typedef __attribute__((ext_vector_type(8))) short bf16x8;
typedef __attribute__((ext_vector_type(4))) float f32x4;

#define GP(p)   ((const __attribute__((address_space(1))) void*)(p))
#define LDSP(p) ((__attribute__((address_space(3))) void*)(p))

__device__ __forceinline__ unsigned bf16pack(float a, float b) {
    unsigned ua = __float_as_uint(a), ub = __float_as_uint(b);
    unsigned ra = (ua + 0x7fffu + ((ua >> 16) & 1u)) >> 16;
    unsigned rb = (ub + 0x7fffu + ((ub >> 16) & 1u)) >> 16;
    return ra | (rb << 16);
}

// ---------------------------------------------------------------------------
// Prep B only (A-prep deleted — main kernel packs A from fp32 inline):
// w -> bf16 row-major + b2. One wave per row; fully coalesced.
// ---------------------------------------------------------------------------
__global__ __launch_bounds__(256) void prep_b_kernel(const float* __restrict__ w,
                                                     uint2* __restrict__ Bbf,
                                                     float* __restrict__ b2) {
    int gid  = blockIdx.x * blockDim.x + threadIdx.x;
    int row  = gid >> 6;
    int lane = gid & 63;
    float4 v = ((const float4*)(w + (size_t)row * NFEAT))[lane];
    Bbf[(size_t)row * 64 + lane] = make_uint2(bf16pack(v.x, v.y), bf16pack(v.z, v.w));
    float s = v.x * v.x + v.y * v.y + v.z * v.z + v.w * v.w;
    #pragma unroll
    for (int off = 32; off > 0; off >>= 1) s += __shfl_down(s, off);
    if (lane == 0) b2[row] = s;
}

// ---------------------------------------------------------------------------
// Main: round-10's proven 48.7 us core (3-deep ring, one barrier per chunk),
// with the A panel loaded DIRECTLY from fp32 xb and packed to bf16 in the
// prologue (removes the whole A-prep kernel + 12 MB of traffic).
// Grid 512 = 32 m-tiles x 16 strips (2 strips/XCD); block 256 = 4 waves
// stacked on rows (wave tile 32 rows x 32 cols -> no cross-wave merge).
// afr[2][8] = 64 VGPR pinned. LDS = 3 x 16 KB ring + b2 4 KB (2 blocks/CU).
// Per chunk h: vmcnt(4) -> barrier -> stage(h+2) -> 16 ds_read + 32 MFMA
// (setprio) -> top-2 fold (6-bit mantissa id). Read swizzle ^((col&7)<<4),
// inverse pre-applied to the staging source (T21 both-sides).
// min-dist == max-(dot - b2/2).
// ---------------------------------------------------------------------------
__global__ __launch_bounds__(256, 2) void som_core(
        const float* __restrict__ xb, const unsigned short* __restrict__ Bbf,
        const float* __restrict__ b2, float* __restrict__ part) {
    __shared__ char smem[53248];    // ring 3 x 16K | b2 strip 4K

    const int t = threadIdx.x, l = t & 63;
    const int wid = t >> 6;                    // wave = 32-row band
    const int x = blockIdx.x & 7, y = blockIdx.x >> 3;
    const int strip = x * 2 + (y >> 5);        // 2 strips per XCD
    const int m0 = (y & 31) * 128;
    const int ns0 = strip * STRIPW;

    // ---- A panel: fp32 xb -> bf16 fragments in 64 VGPRs (packed inline) ----
    // lane l, frag (mf,kk): row m0+wid*32+mf*16+(l&15), k = kk*32+(l>>4)*8..+8
    const float* gA = xb + (size_t)(m0 + wid * 32 + (l & 15)) * NFEAT + (l >> 4) * 8;
    bf16x8 afr[2][8];
    #pragma unroll
    for (int mf = 0; mf < 2; ++mf)
        #pragma unroll
        for (int kk = 0; kk < 8; ++kk) {
            float4 f0 = *(const float4*)(gA + (size_t)mf * 16 * NFEAT + kk * 32);
            float4 f1 = *(const float4*)(gA + (size_t)mf * 16 * NFEAT + kk * 32 + 4);
            uint4 u;
            u.x = bf16pack(f0.x, f0.y);
            u.y = bf16pack(f0.z, f0.w);
            u.z = bf16pack(f1.x, f1.y);
            u.w = bf16pack(f1.z, f1.w);
            afr[mf][kk] = __builtin_bit_cast(bf16x8, u);
        }

    // ---- staging: chunk = 32 cols x 512 B = 16 KB = 4 ops/thread ----
    // op i: col = i*8 + (t>>5), in-row byte (t&31)*16, swizzle ((col&7)<<4)
    // pre-applied to the SOURCE (LDS dest linear, T21 both-sides rule).
    const int sbyte = ((t & 31) * 16) ^ ((t >> 5) << 4);
    const char* gBs = (const char*)Bbf + (size_t)(ns0 + (t >> 5)) * 512 + sbyte;
#define STAGE(dstb, c) {                                                         \
        const char* s_ = gBs + (size_t)(c) * 16384;                              \
        char* d_ = (dstb) + t * 16;                                              \
        __builtin_amdgcn_global_load_lds(GP(s_),         LDSP(d_),         16,0,0); \
        __builtin_amdgcn_global_load_lds(GP(s_ + 4096),  LDSP(d_ + 4096),  16,0,0); \
        __builtin_amdgcn_global_load_lds(GP(s_ + 8192),  LDSP(d_ + 8192),  16,0,0); \
        __builtin_amdgcn_global_load_lds(GP(s_ + 12288), LDSP(d_ + 12288), 16,0,0); }

    // prologue: b2 strip (1 op) then chunks 0,1 -> slots 0,1 (9 in flight)
    __builtin_amdgcn_global_load_lds(GP((const char*)b2 + (size_t)ns0 * 4 + t * 16),
                                     LDSP(smem + 49152 + t * 16), 16, 0, 0);
    STAGE(smem,         0)
    STAGE(smem + 16384, 1)

    // pin A fragments (packed values stay live across the loop)
    #pragma unroll
    for (int mf = 0; mf < 2; ++mf)
        #pragma unroll
        for (int kk = 0; kk < 8; ++kk)
            asm volatile("" : "+v"(afr[mf][kk]));

    float r0[2][4], r1[2][4];
    #pragma unroll
    for (int mf = 0; mf < 2; ++mf)
        #pragma unroll
        for (int j = 0; j < 4; ++j) { r0[mf][j] = -FLT_MAX; r1[mf][j] = -FLT_MAX; }

    char* pr = smem;                 // read slot (chunk h)
    char* pm = smem + 16384;         // next     (chunk h+1)
    char* ps = smem + 32768;         // stage target (chunk h+2)
    const int rswz = (l & 7) << 4;
    const int cb = (l & 15) * 512;

    for (int h = 0; h < NH; ++h) {
        if (h < NH - 1) asm volatile("s_waitcnt vmcnt(4)" ::: "memory");
        else            asm volatile("s_waitcnt vmcnt(0)" ::: "memory");
        __builtin_amdgcn_s_barrier();   // chunk h visible; h-1 readers done
        asm volatile("" ::: "memory");

        if (h + 2 < NH) STAGE(ps, h + 2)   // slot freed by compute(h-1)

        const int c0 = h * 32 + (l & 15);
        const float b20 = -0.5f * *(const float*)(smem + 49152 + c0 * 4);
        const float b21 = -0.5f * *(const float*)(smem + 49152 + c0 * 4 + 64);
        f32x4 acc[2][2];
        #pragma unroll
        for (int mf = 0; mf < 2; ++mf) {
            acc[mf][0] = (f32x4){b20, b20, b20, b20};
            acc[mf][1] = (f32x4){b21, b21, b21, b21};
        }

        __builtin_amdgcn_s_setprio(1);
        #pragma unroll
        for (int kk = 0; kk < 8; ++kk) {
            const int ko = (kk * 64 + (l >> 4) * 16) ^ rswz;
            bf16x8 bf0 = *(const bf16x8*)(pr + cb + ko);
            bf16x8 bf1 = *(const bf16x8*)(pr + 8192 + cb + ko);
            #pragma unroll
            for (int mf = 0; mf < 2; ++mf) {
                acc[mf][0] = __builtin_amdgcn_mfma_f32_16x16x32_bf16(afr[mf][kk], bf0, acc[mf][0], 0, 0, 0);
                acc[mf][1] = __builtin_amdgcn_mfma_f32_16x16x32_bf16(afr[mf][kk], bf1, acc[mf][1], 0, 0, 0);
            }
        }
        __builtin_amdgcn_s_setprio(0);

        // top-2 fold: 6-bit id (h*2 + nf) in low mantissa bits
        #pragma unroll
        for (int nf = 0; nf < 2; ++nf) {
            const unsigned idn = (unsigned)(h * 2 + nf);
            #pragma unroll
            for (int mf = 0; mf < 2; ++mf)
                #pragma unroll
                for (int j = 0; j < 4; ++j) {
                    float p = __uint_as_float((__float_as_uint(acc[mf][nf][j]) & 0xFFFFFFC0u) | idn);
                    float nr1 = __builtin_amdgcn_fmed3f(r0[mf][j], r1[mf][j], p);
                    r0[mf][j] = fmaxf(r0[mf][j], p);
                    r1[mf][j] = nr1;
                }
        }

        char* tp = pr; pr = pm; pm = ps; ps = tp;   // rotate ring
    }

    // ---- per-row merge over 16 lane-cols (10-bit repack); direct write ----
    #pragma unroll
    for (int mf = 0; mf < 2; ++mf)
        #pragma unroll
        for (int j = 0; j < 4; ++j) {
            unsigned u0 = __float_as_uint(r0[mf][j]);
            unsigned u1 = __float_as_uint(r1[mf][j]);
            u0 = (u0 & 0xFFFFFC00u) | ((u0 & 63u) << 4) | (unsigned)(l & 15);
            u1 = (u1 & 0xFFFFFC00u) | ((u1 & 63u) << 4) | (unsigned)(l & 15);
            float v0 = __uint_as_float(u0), v1 = __uint_as_float(u1);
            #pragma unroll
            for (int off = 1; off < 16; off <<= 1) {
                float o0 = __shfl_xor(v0, off), o1 = __shfl_xor(v1, off);
                float nv1 = fmaxf(fminf(v0, o0), fmaxf(v1, o1));
                v0 = fmaxf(v0, o0);
                v1 = nv1;
            }
            if ((l & 15) == 0) {
                int row = m0 + wid * 32 + mf * 16 + (l >> 4) * 4 + j;
                ((float2*)part)[(size_t)row * NSTRIP + strip] = make_float2(v0, v1);
            }
        }
#undef STAGE
}

// ---------------------------------------------------------------------------
// Refine: 1 wave per row over 32 packed entries; a2 computed INLINE from the
// xb row (a2 kernel deleted); exact fp32+sqrt recompute within margin.
// ---------------------------------------------------------------------------
__global__ __launch_bounds__(256) void refine_kernel(
        const float* __restrict__ xb, const float* __restrict__ w,
        const float* __restrict__ b2, const float* __restrict__ part,
        int* __restrict__ out) {
    const int t = threadIdx.x, l = t & 63;
    const int row = blockIdx.x * 4 + (t >> 6);

    const float* pr = part + (size_t)row * (NSTRIP * 2);
    float v = (l < NSTRIP * 2) ? pr[l] : -FLT_MAX;
    float mx = v;
    #pragma unroll
    for (int off = 1; off < 64; off <<= 1) mx = fmaxf(mx, __shfl_xor(mx, off));
    const float cut = mx - UMARGIN;

    unsigned long long key = ~0ull;
    if (l < NSTRIP * 2 && v >= cut) {
        unsigned b = __float_as_uint(v);
        int lane4 = b & 15, id6 = (b >> 4) & 63;
        int col = (l >> 1) * STRIPW + (id6 >> 1) * 32 + (id6 & 1) * 16 + lane4;
        const float4* xr = (const float4*)(xb + (size_t)row * NFEAT);
        const float4* wr = (const float4*)(w + (size_t)col * NFEAT);
        float s0 = 0.f, s1 = 0.f, aa = 0.f;
        #pragma unroll
        for (int k = 0; k < 32; ++k) {
            float4 x0 = xr[2 * k + 0], w0 = wr[2 * k + 0];
            float4 x1 = xr[2 * k + 1], w1 = wr[2 * k + 1];
            s0 += x0.x * w0.x + x0.y * w0.y + x0.z * w0.z + x0.w * w0.w;
            s1 += x1.x * w1.x + x1.y * w1.y + x1.z * w1.z + x1.w * w1.w;
            aa += x0.x * x0.x + x0.y * x0.y + x0.z * x0.z + x0.w * x0.w
                + x1.x * x1.x + x1.y * x1.y + x1.z * x1.z + x1.w * x1.w;
        }
        float dot = s0 + s1;
        float dd = aa + b2[col] - 2.f * dot;
        float s = sqrtf(fmaxf(dd, 0.f));
        key = ((unsigned long long)__float_as_uint(s) << 32) | (unsigned)col;
    }
    #pragma unroll
    for (int off = 1; off < 64; off <<= 1) {
        unsigned long long o = __shfl_xor(key, off);
        key = o < key ? o : key;
    }
    if (l == 0) {
        int idx = (int)(key & 0xffffffffu);
        out[2 * row]     = idx >> 7;
        out[2 * row + 1] = idx & 127;
    }
}

extern "C" void kernel_launch(void* const* d_in, const int* in_sizes, int n_in,
                              void* d_out, int out_size, void* d_ws, size_t ws_size,
                              hipStream_t stream) {
    const float* xb = (const float*)d_in[0];   // (4096, 256)
    const float* w  = (const float*)d_in[1];   // (16384, 256)
    int* out = (int*)d_out;

    char* ws = (char*)d_ws;
    unsigned short* Bbf = (unsigned short*)ws;                 // 8 MB row-major
    float* b2   = (float*)(ws + (8u << 20));                   // 64 KB
    float* part = (float*)(ws + (8u << 20) + (64u << 10));     // 512 KB

    prep_b_kernel<<<(MTOT * 64) / 256, 256, 0, stream>>>(w, (uint2*)Bbf, b2);
    som_core<<<512, 256, 0, stream>>>(xb, Bbf, b2, part);
    refine_kernel<<<BATCH / 4, 256, 0, stream>>>(xb, w, b2, part, out);
}